// Round 6
// baseline (24572.099 us; speedup 1.0000x reference)
//
#include <hip/hip_runtime.h>
#include <math.h>

// Persistent-kernel LSTM: H=2048, SEQ=4096, fp32 (no fp32 MFMA -> vector ALU).
// 256 WGs x 512 thr, 1 WG/CU. Wave w of WG g owns hidden unit k=g*8+w; each
// lane holds 4 gate-rows x 32 cols of W_hh (128 floats, VGPR/AGPR unified).
//
// Cross-step exchange v4 (tagged data, line-per-WG, poll==read):
//   hline[2][256][16]: one 64B cacheline per producer WG per slot; words
//   [0..8) = that WG's 8 h values as fp32 with low 8 mantissa bits = step
//   tag (t+1)&0xFF; [8..16) pad. A line receives all 8 stores in a tight
//   window from one WG -> ~1 consumer refill (R5's packed layout took ~16
//   staggered refills/line from 2 WGs = the regression cause).
//   Consumer thread tid polls exactly its 4 contiguous units (line tid>>1,
//   half (tid&1)*4) with tag validation + s_sleep backoff; the successful
//   poll IS the data read. No producer drain, no flags, 1 barrier/step.
//   ABA-safe: parity slots + lockstep (publish t+1 causally follows every
//   consumer's t-read) -> candidate stale tags differ by +/-2 mod 256.
// y_{t-2} drained by WG0/tid0 each step from LDS partials. d_ws: 32 KB.

#define HDIM 2048
#define SEQ 4096
#define NWG 256
#define TPB 512
#define SLOTW 4096   // unsigned words per slot: 256 lines x 16

__device__ __forceinline__ float sigmoidf_(float x) {
  return 1.0f / (1.0f + expf(-x));
}
__device__ __forceinline__ float tanh_(float x) {
  float e = expf(-2.0f * fabsf(x));
  float r = (1.0f - e) / (1.0f + e);
  return copysignf(r, x);
}

// zero BOTH slots (harness poisons d_ws with 0xAA = tag 170 -> must clear)
__global__ void lstm_init(unsigned* hline) {
  const int i = blockIdx.x * 256 + threadIdx.x;   // 32 blocks x 256 = 8192
  hline[i] = 0u;
}

__global__ __launch_bounds__(TPB, 2) void lstm_persist(
    const float* __restrict__ x, const float* __restrict__ w_ih,
    const float* __restrict__ w_hh, const float* __restrict__ b_ih,
    const float* __restrict__ b_hh, const float* __restrict__ w_out,
    const float* __restrict__ b_out, float* __restrict__ out,
    unsigned* __restrict__ hline)
{
  const int wg   = blockIdx.x;
  const int tid  = threadIdx.x;
  const int wave = tid >> 6;
  const int lane = tid & 63;
  const int k    = wg * 8 + wave;   // this wave's hidden unit
  // this thread's consumer slice: units [4*tid, 4*tid+4) ->
  // line tid>>1, word offset (tid&1)*4 within the line
  const int pofs = (tid >> 1) * 16 + (tid & 1) * 4;

  __shared__ float xs[SEQ];        // 16 KB
  __shared__ float hs[2][HDIM];    // 16 KB, double-buffered
  __shared__ float wys[2][8];      // per-wave y partials, double-buffered

  // ---- one-time: weights into registers ----
  // rows g=0..3 (gates i,f,g,o of unit k): row = k + g*HDIM
  // cols per lane: {256*j + 4*lane + q}, j=0..7, q=0..3  -> 32 float4
  float4 W[32];
  float wx[4], bb[4];
  #pragma unroll
  for (int g = 0; g < 4; ++g) {
    const int row = k + g * HDIM;
    const float* rp = w_hh + (size_t)row * HDIM + lane * 4;
    #pragma unroll
    for (int j = 0; j < 8; ++j)
      W[g * 8 + j] = *(const float4*)(rp + j * 256);
    wx[g] = w_ih[row];
    bb[g] = b_ih[row] + b_hh[row];
  }
  float wo[4];
  #pragma unroll
  for (int q = 0; q < 4; ++q) wo[q] = w_out[4 * tid + q];
  const float bout = b_out[0];

  for (int i = tid; i < SEQ; i += TPB) xs[i] = x[i];

  float cc = 0.f, hh = 0.f;
  float hv[4];
  __syncthreads();

  for (int t = 0; t < SEQ; ++t) {
    const int par = t & 1;
    const unsigned want = (unsigned)t & 0xFFu;

    // ---- poll own 4 values (tag byte == t&0xFF); poll IS the read ----
    {
      const unsigned* src = hline + (par ^ 1) * SLOTW + pofs;
      unsigned v0, v1, v2, v3;
      int guard = 0;
      for (;;) {
        v0 = __hip_atomic_load(&src[0], __ATOMIC_RELAXED,
                               __HIP_MEMORY_SCOPE_AGENT);
        v1 = __hip_atomic_load(&src[1], __ATOMIC_RELAXED,
                               __HIP_MEMORY_SCOPE_AGENT);
        v2 = __hip_atomic_load(&src[2], __ATOMIC_RELAXED,
                               __HIP_MEMORY_SCOPE_AGENT);
        v3 = __hip_atomic_load(&src[3], __ATOMIC_RELAXED,
                               __HIP_MEMORY_SCOPE_AGENT);
        const int ok = ((v0 & 0xFFu) == want) & ((v1 & 0xFFu) == want) &
                       ((v2 & 0xFFu) == want) & ((v3 & 0xFFu) == want);
        if (ok) break;
        __builtin_amdgcn_s_sleep(1);
        if (++guard > (1 << 14)) break;   // protocol-failure escape
      }
      hv[0] = __uint_as_float(v0);
      hv[1] = __uint_as_float(v1);
      hv[2] = __uint_as_float(v2);
      hv[3] = __uint_as_float(v3);
    }

    // ---- stage to LDS (one ds_write_b128), single barrier per step ----
    *(float4*)&hs[par][4 * tid] = make_float4(hv[0], hv[1], hv[2], hv[3]);
    __syncthreads();  // B: hs[par] fully staged; wys[par^1] stable

    // ---- drain y_{t-2} (wys[par^1] written during step t-1) ----
    if (t >= 2 && wg == 0 && tid == 0)
      out[t - 2] = wys[par ^ 1][0] + wys[par ^ 1][1] + wys[par ^ 1][2] +
                   wys[par ^ 1][3] + wys[par ^ 1][4] + wys[par ^ 1][5] +
                   wys[par ^ 1][6] + wys[par ^ 1][7] + bout;

    // ---- z = W_hh @ h (per-lane partials over 32 columns) ----
    float acc[4] = {0.f, 0.f, 0.f, 0.f};
    #pragma unroll
    for (int j = 0; j < 8; ++j) {
      const float4 h4 = *(const float4*)&hs[par][j * 256 + lane * 4];
      #pragma unroll
      for (int g = 0; g < 4; ++g) {
        const float4 w = W[g * 8 + j];
        acc[g] = fmaf(w.x, h4.x, acc[g]);
        acc[g] = fmaf(w.y, h4.y, acc[g]);
        acc[g] = fmaf(w.z, h4.z, acc[g]);
        acc[g] = fmaf(w.w, h4.w, acc[g]);
      }
    }
    // ---- 64-lane butterfly: all lanes end with full row sums ----
    #pragma unroll
    for (int off = 32; off >= 1; off >>= 1) {
      #pragma unroll
      for (int g = 0; g < 4; ++g)
        acc[g] += __shfl_xor(acc[g], off, 64);
    }

    const float xt = xs[t];
    float z[4];
    #pragma unroll
    for (int g = 0; g < 4; ++g) z[g] = fmaf(xt, wx[g], acc[g] + bb[g]);

    // ---- gates (lane-redundant, identical values) ----
    const float gi = sigmoidf_(z[0]), gf = sigmoidf_(z[1]);
    const float gg = tanh_(z[2]), go = sigmoidf_(z[3]);
    cc = gf * cc + gi * gg;
    hh = go * tanh_(cc);

    // ---- publish h_t: tagged fp32 into this WG's line of slot par ----
    if (lane == 0) {
      const unsigned bits = (__float_as_uint(hh) & ~0xFFu) |
                            (((unsigned)(t + 1)) & 0xFFu);
      __hip_atomic_store(&hline[par * SLOTW + wg * 16 + wave], bits,
                         __ATOMIC_RELAXED, __HIP_MEMORY_SCOPE_AGENT);
    }

    // ---- off-path: y_{t-1} partial from hv (h_{t-1}) ----
    float sy = 0.f;
    #pragma unroll
    for (int q = 0; q < 4; ++q) sy = fmaf(wo[q], hv[q], sy);
    #pragma unroll
    for (int off = 32; off >= 1; off >>= 1) sy += __shfl_xor(sy, off, 64);
    if (lane == 0) wys[par][wave] = sy;
  }

  // ---- epilogue ----
  __syncthreads();  // wys[1] (y partials of h_{SEQ-2}) complete
  if (wg == 0 && tid == 0)
    out[SEQ - 2] = wys[1][0] + wys[1][1] + wys[1][2] + wys[1][3] + wys[1][4] +
                   wys[1][5] + wys[1][6] + wys[1][7] + bout;

  if (wg == 0) {
    // poll h_{SEQ-1}: slot (SEQ-1)&1 = 1, tag = SEQ&0xFF = 0
    const unsigned want = ((unsigned)SEQ) & 0xFFu;
    const unsigned* src = hline + SLOTW + pofs;
    unsigned v0 = 0, v1 = 0, v2 = 0, v3 = 0;
    int guard = 0;
    for (;;) {
      v0 = __hip_atomic_load(&src[0], __ATOMIC_RELAXED,
                             __HIP_MEMORY_SCOPE_AGENT);
      v1 = __hip_atomic_load(&src[1], __ATOMIC_RELAXED,
                             __HIP_MEMORY_SCOPE_AGENT);
      v2 = __hip_atomic_load(&src[2], __ATOMIC_RELAXED,
                             __HIP_MEMORY_SCOPE_AGENT);
      v3 = __hip_atomic_load(&src[3], __ATOMIC_RELAXED,
                             __HIP_MEMORY_SCOPE_AGENT);
      const int ok = ((v0 & 0xFFu) == want) & ((v1 & 0xFFu) == want) &
                     ((v2 & 0xFFu) == want) & ((v3 & 0xFFu) == want);
      if (ok) break;
      __builtin_amdgcn_s_sleep(1);
      if (++guard > (1 << 14)) break;
    }
    float sy = 0.f;
    sy = fmaf(wo[0], __uint_as_float(v0), sy);
    sy = fmaf(wo[1], __uint_as_float(v1), sy);
    sy = fmaf(wo[2], __uint_as_float(v2), sy);
    sy = fmaf(wo[3], __uint_as_float(v3), sy);
    #pragma unroll
    for (int off = 32; off >= 1; off >>= 1) sy += __shfl_xor(sy, off, 64);
    if (lane == 0) wys[0][wave] = sy;
    __syncthreads();
    if (tid == 0)
      out[SEQ - 1] = wys[0][0] + wys[0][1] + wys[0][2] + wys[0][3] +
                     wys[0][4] + wys[0][5] + wys[0][6] + wys[0][7] + bout;
  }

  // ---- final h, c (exact local fp32 state) ----
  if (lane == 0) {
    out[SEQ + k] = hh;
    out[SEQ + HDIM + k] = cc;
  }
}

extern "C" void kernel_launch(void* const* d_in, const int* in_sizes, int n_in,
                              void* d_out, int out_size, void* d_ws, size_t ws_size,
                              hipStream_t stream) {
  const float* x     = (const float*)d_in[0];
  const float* w_ih  = (const float*)d_in[1];
  const float* w_hh  = (const float*)d_in[2];
  const float* b_ih  = (const float*)d_in[3];
  const float* b_hh  = (const float*)d_in[4];
  const float* w_out = (const float*)d_in[5];
  const float* b_out = (const float*)d_in[6];
  float* out = (float*)d_out;

  // ws layout: [0, 32KB): hline[2][256][16] tagged fp32 (64B line per WG)
  unsigned* hline = (unsigned*)d_ws;

  lstm_init<<<32, 256, 0, stream>>>(hline);
  lstm_persist<<<NWG, TPB, 0, stream>>>(x, w_ih, w_hh, b_ih, b_hh, w_out,
                                        b_out, out, hline);
}

// Round 7
// 12243.878 us; speedup vs baseline: 2.0069x; 2.0069x over previous
//
#include <hip/hip_runtime.h>
#include <math.h>

// Persistent-kernel LSTM: H=2048, SEQ=4096, fp32 (no fp32 MFMA -> vector ALU).
// 256 WGs x 512 thr, 1 WG/CU. Wave w of WG g owns hidden unit k=g*8+w; each
// lane holds 4 gate-rows x 32 cols of W_hh (128 floats, VGPR/AGPR unified).
//
// Cross-step exchange v5 (tagged data, line-per-WG, SINGLE-TRANSACTION pub):
//   hline[2][256][16]: one 64B line per producer WG per slot; words [0..8) =
//   the WG's 8 h values as fp32 with low mantissa byte = tag (t+1)&0xFF.
//   Producer: waves drop h into LDS pub[8]; barrier; wave0 lanes 0..3 issue
//   four 8B agent atomic stores in ONE wave instruction -> one coalesced 32B
//   transaction -> ONE remote-L2 invalidation per line per step (R6 had 8
//   separate stores/line => ~2.2 refills/line/XCD churn, 6us/step).
//   Consumer thread tid polls its own 16B quad (2x 8B atomic loads, line
//   tid>>1, half tid&1) with per-word tag validation; poll IS the read; torn
//   views impossible to mis-consume (every word carries its tag).
//   ABA-safe: parity slots + lockstep => stale tags differ by 2 mod 256.
// y_{t-2} drained by WG0/tid0 each step from LDS partials. d_ws: 32 KB.

#define HDIM 2048
#define SEQ 4096
#define NWG 256
#define TPB 512
#define SLOTW 4096   // unsigned words per slot: 256 lines x 16

__device__ __forceinline__ float sigmoidf_(float x) {
  return 1.0f / (1.0f + expf(-x));
}
__device__ __forceinline__ float tanh_(float x) {
  float e = expf(-2.0f * fabsf(x));
  float r = (1.0f - e) / (1.0f + e);
  return copysignf(r, x);
}

// zero BOTH slots (harness poisons d_ws with 0xAA)
__global__ void lstm_init(unsigned* hline) {
  const int i = blockIdx.x * 256 + threadIdx.x;   // 32 blocks x 256 = 8192
  hline[i] = 0u;
}

__global__ __launch_bounds__(TPB, 2) void lstm_persist(
    const float* __restrict__ x, const float* __restrict__ w_ih,
    const float* __restrict__ w_hh, const float* __restrict__ b_ih,
    const float* __restrict__ b_hh, const float* __restrict__ w_out,
    const float* __restrict__ b_out, float* __restrict__ out,
    unsigned* __restrict__ hline)
{
  const int wg   = blockIdx.x;
  const int tid  = threadIdx.x;
  const int wave = tid >> 6;
  const int lane = tid & 63;
  const int k    = wg * 8 + wave;   // this wave's hidden unit
  // consumer quad: units [4*tid, 4*tid+4) = line tid>>1, half tid&1
  // in 8B units: offset (tid>>1)*8 + (tid&1)*2
  const int qofs = (tid >> 1) * 8 + (tid & 1) * 2;

  __shared__ float xs[SEQ];        // 16 KB
  __shared__ float hs[2][HDIM];    // 16 KB, double-buffered
  __shared__ float wys[2][8];      // per-wave y partials, double-buffered
  __shared__ float pub[8];         // gather of this WG's 8 h values

  // ---- one-time: weights into registers ----
  // rows g=0..3 (gates i,f,g,o of unit k): row = k + g*HDIM
  // cols per lane: {256*j + 4*lane + q}, j=0..7, q=0..3  -> 32 float4
  float4 W[32];
  float wx[4], bb[4];
  #pragma unroll
  for (int g = 0; g < 4; ++g) {
    const int row = k + g * HDIM;
    const float* rp = w_hh + (size_t)row * HDIM + lane * 4;
    #pragma unroll
    for (int j = 0; j < 8; ++j)
      W[g * 8 + j] = *(const float4*)(rp + j * 256);
    wx[g] = w_ih[row];
    bb[g] = b_ih[row] + b_hh[row];
  }
  float wo[4];
  #pragma unroll
  for (int q = 0; q < 4; ++q) wo[q] = w_out[4 * tid + q];
  const float bout = b_out[0];

  for (int i = tid; i < SEQ; i += TPB) xs[i] = x[i];

  float cc = 0.f, hh = 0.f;
  float hv[4];
  __syncthreads();

  for (int t = 0; t < SEQ; ++t) {
    const int par = t & 1;
    const unsigned want = (unsigned)t & 0xFFu;

    // ---- poll own quad: 2x 8B loads, all 4 tag bytes == t&0xFF ----
    {
      const unsigned long long* src =
          (const unsigned long long*)(hline + (par ^ 1) * SLOTW) + qofs;
      unsigned long long a, b;
      int guard = 0;
      for (;;) {
        a = __hip_atomic_load(&src[0], __ATOMIC_RELAXED,
                              __HIP_MEMORY_SCOPE_AGENT);
        b = __hip_atomic_load(&src[1], __ATOMIC_RELAXED,
                              __HIP_MEMORY_SCOPE_AGENT);
        const int ok = (((unsigned)a & 0xFFu) == want) &
                       (((unsigned)(a >> 32) & 0xFFu) == want) &
                       (((unsigned)b & 0xFFu) == want) &
                       (((unsigned)(b >> 32) & 0xFFu) == want);
        if (ok) break;
        __builtin_amdgcn_s_sleep(1);
        if (++guard > (1 << 14)) break;   // protocol-failure escape
      }
      hv[0] = __uint_as_float((unsigned)a);
      hv[1] = __uint_as_float((unsigned)(a >> 32));
      hv[2] = __uint_as_float((unsigned)b);
      hv[3] = __uint_as_float((unsigned)(b >> 32));
    }

    // ---- stage to LDS (one ds_write_b128) ----
    *(float4*)&hs[par][4 * tid] = make_float4(hv[0], hv[1], hv[2], hv[3]);
    __syncthreads();  // B1: hs[par] fully staged; wys[par^1] stable

    // ---- drain y_{t-2} (wys[par^1] written during step t-1) ----
    if (t >= 2 && wg == 0 && tid == 0)
      out[t - 2] = wys[par ^ 1][0] + wys[par ^ 1][1] + wys[par ^ 1][2] +
                   wys[par ^ 1][3] + wys[par ^ 1][4] + wys[par ^ 1][5] +
                   wys[par ^ 1][6] + wys[par ^ 1][7] + bout;

    // ---- z = W_hh @ h (per-lane partials over 32 columns) ----
    float acc[4] = {0.f, 0.f, 0.f, 0.f};
    #pragma unroll
    for (int j = 0; j < 8; ++j) {
      const float4 h4 = *(const float4*)&hs[par][j * 256 + lane * 4];
      #pragma unroll
      for (int g = 0; g < 4; ++g) {
        const float4 w = W[g * 8 + j];
        acc[g] = fmaf(w.x, h4.x, acc[g]);
        acc[g] = fmaf(w.y, h4.y, acc[g]);
        acc[g] = fmaf(w.z, h4.z, acc[g]);
        acc[g] = fmaf(w.w, h4.w, acc[g]);
      }
    }
    // ---- 64-lane butterfly: all lanes end with full row sums ----
    #pragma unroll
    for (int off = 32; off >= 1; off >>= 1) {
      #pragma unroll
      for (int g = 0; g < 4; ++g)
        acc[g] += __shfl_xor(acc[g], off, 64);
    }

    const float xt = xs[t];
    float z[4];
    #pragma unroll
    for (int g = 0; g < 4; ++g) z[g] = fmaf(xt, wx[g], acc[g] + bb[g]);

    // ---- gates (lane-redundant, identical values) ----
    const float gi = sigmoidf_(z[0]), gf = sigmoidf_(z[1]);
    const float gg = tanh_(z[2]), go = sigmoidf_(z[3]);
    cc = gf * cc + gi * gg;
    hh = go * tanh_(cc);

    // ---- off-path: y_{t-1} partial from hv (h_{t-1}) ----
    float sy = 0.f;
    #pragma unroll
    for (int q = 0; q < 4; ++q) sy = fmaf(wo[q], hv[q], sy);
    #pragma unroll
    for (int off = 32; off >= 1; off >>= 1) sy += __shfl_xor(sy, off, 64);
    if (lane == 0) {
      wys[par][wave] = sy;
      pub[wave] = hh;   // gather for single-transaction publish
    }
    __syncthreads();  // B2: pub[0..8) complete

    // ---- publish: wave0 lanes 0..3, four 8B stores = ONE 32B transaction ----
    if (wave == 0 && lane < 4) {
      const unsigned tg = (unsigned)(t + 1) & 0xFFu;
      const unsigned ua = (__float_as_uint(pub[2 * lane]) & ~0xFFu) | tg;
      const unsigned ub = (__float_as_uint(pub[2 * lane + 1]) & ~0xFFu) | tg;
      const unsigned long long pay =
          (unsigned long long)ua | ((unsigned long long)ub << 32);
      __hip_atomic_store(
          (unsigned long long*)(hline + par * SLOTW + wg * 16) + lane, pay,
          __ATOMIC_RELAXED, __HIP_MEMORY_SCOPE_AGENT);
    }
  }

  // ---- epilogue ----
  __syncthreads();  // wys[1] (y partials of h_{SEQ-2}) complete
  if (wg == 0 && tid == 0)
    out[SEQ - 2] = wys[1][0] + wys[1][1] + wys[1][2] + wys[1][3] + wys[1][4] +
                   wys[1][5] + wys[1][6] + wys[1][7] + bout;

  if (wg == 0) {
    // poll h_{SEQ-1}: slot (SEQ-1)&1 = 1, tag = SEQ&0xFF = 0
    const unsigned want = ((unsigned)SEQ) & 0xFFu;
    const unsigned long long* src =
        (const unsigned long long*)(hline + SLOTW) + qofs;
    unsigned long long a = 0, b = 0;
    int guard = 0;
    for (;;) {
      a = __hip_atomic_load(&src[0], __ATOMIC_RELAXED,
                            __HIP_MEMORY_SCOPE_AGENT);
      b = __hip_atomic_load(&src[1], __ATOMIC_RELAXED,
                            __HIP_MEMORY_SCOPE_AGENT);
      const int ok = (((unsigned)a & 0xFFu) == want) &
                     (((unsigned)(a >> 32) & 0xFFu) == want) &
                     (((unsigned)b & 0xFFu) == want) &
                     (((unsigned)(b >> 32) & 0xFFu) == want);
      if (ok) break;
      __builtin_amdgcn_s_sleep(1);
      if (++guard > (1 << 14)) break;
    }
    float sy = 0.f;
    sy = fmaf(wo[0], __uint_as_float((unsigned)a), sy);
    sy = fmaf(wo[1], __uint_as_float((unsigned)(a >> 32)), sy);
    sy = fmaf(wo[2], __uint_as_float((unsigned)b), sy);
    sy = fmaf(wo[3], __uint_as_float((unsigned)(b >> 32)), sy);
    #pragma unroll
    for (int off = 32; off >= 1; off >>= 1) sy += __shfl_xor(sy, off, 64);
    if (lane == 0) wys[0][wave] = sy;
    __syncthreads();
    if (tid == 0)
      out[SEQ - 1] = wys[0][0] + wys[0][1] + wys[0][2] + wys[0][3] +
                     wys[0][4] + wys[0][5] + wys[0][6] + wys[0][7] + bout;
  }

  // ---- final h, c (exact local fp32 state) ----
  if (lane == 0) {
    out[SEQ + k] = hh;
    out[SEQ + HDIM + k] = cc;
  }
}

extern "C" void kernel_launch(void* const* d_in, const int* in_sizes, int n_in,
                              void* d_out, int out_size, void* d_ws, size_t ws_size,
                              hipStream_t stream) {
  const float* x     = (const float*)d_in[0];
  const float* w_ih  = (const float*)d_in[1];
  const float* w_hh  = (const float*)d_in[2];
  const float* b_ih  = (const float*)d_in[3];
  const float* b_hh  = (const float*)d_in[4];
  const float* w_out = (const float*)d_in[5];
  const float* b_out = (const float*)d_in[6];
  float* out = (float*)d_out;

  // ws layout: [0, 32KB): hline[2][256][16] tagged fp32 (64B line per WG)
  unsigned* hline = (unsigned*)d_ws;

  lstm_init<<<32, 256, 0, stream>>>(hline);
  lstm_persist<<<NWG, TPB, 0, stream>>>(x, w_ih, w_hh, b_ih, b_hh, w_out,
                                        b_out, out, hline);
}